// Round 1
// baseline (930.233 us; speedup 1.0000x reference)
//
#include <hip/hip_runtime.h>
#include <math.h>

#define N_   2048
#define SEQ_ 128
#define E_   512
#define R_   128
#define NR_  (N_ * R_)

typedef __attribute__((ext_vector_type(8))) short short8;
typedef __attribute__((ext_vector_type(4))) float f32x4;

typedef __attribute__((address_space(3))) void lds_t;
typedef __attribute__((address_space(1))) const void glb_t;

__device__ __forceinline__ void async16(void* l, const void* g) {
    // 16B per lane: LDS dest = uniform base + lane*16; global src per-lane.
    __builtin_amdgcn_global_load_lds((glb_t*)g, (lds_t*)l, 16, 0, 0);
}

__device__ __forceinline__ ushort f2bf(float f) {
    union { float f; uint u; } v; v.f = f;
    uint r = v.u + 0x7FFFu + ((v.u >> 16) & 1u);   // RNE
    return (ushort)(r >> 16);
}
__device__ __forceinline__ float fast_tanhf(float x) {
    float ax = fabsf(x);
    float t = __expf(-2.f * ax);
    float r = (1.f - t) / (1.f + t);
    return copysignf(r, x);
}

// ---- prep: W^T bf16: three ExR -> [128][512]; two RxR -> [128][128];
//      plus c2[ps][r] = sum_k tanh(b1[k]) * W2[k][r] (constant-row correction) ----
__global__ void prep_kernel(const float* __restrict__ W1p, const float* __restrict__ W1n,
                            const float* __restrict__ Wa,  const float* __restrict__ W2p,
                            const float* __restrict__ W2n, const float* __restrict__ b1p,
                            const float* __restrict__ b1n, ushort* __restrict__ WT,
                            float* __restrict__ c2)
{
    if (blockIdx.x == 896) {
        int t = threadIdx.x;               // 0..255
        int ps = t >> 7, r = t & 127;
        const float* W2 = ps ? W2n : W2p;
        const float* b1 = ps ? b1n : b1p;
        float s = 0.f;
        for (int k = 0; k < 128; ++k)
            s += tanhf(b1[k]) * W2[k * R_ + r];
        c2[ps * R_ + r] = s;
        return;
    }
    int idx = blockIdx.x * 256 + threadIdx.x;      // 0..229375
    if (idx < 196608) {
        int m = idx >> 16;
        int o = idx & 65535;
        int r = o >> 9, e = o & 511;
        const float* src = (m == 0) ? W1p : (m == 1) ? W1n : Wa;
        WT[idx] = f2bf(src[e * R_ + r]);
    } else if (idx < 229376) {
        int o = idx - 196608;
        int m = o >> 14;
        int p = o & 16383;
        int r = p >> 7, e = p & 127;
        const float* src = (m == 0) ? W2p : W2n;
        WT[idx] = f2bf(src[e * R_ + r]);
    }
}

// One block per (n, half): 64 t-rows x 128 r, 4 waves (wave = 32 r-cols).
// XOR swizzle everywhere; counted-vmcnt barriers keep next-chunk X prefetch in flight;
// region-based tile skipping drops dead P/N MFMAs (masked rows give analytic constants).
__global__ __launch_bounds__(256, 2)
void mlp_mfma_kernel(const int* __restrict__ C, const float* __restrict__ L,
                     const float* __restrict__ Pw, const float* __restrict__ Nw,
                     const float* __restrict__ b1p, const float* __restrict__ b2p,
                     const float* __restrict__ b1n, const float* __restrict__ b2n,
                     const float* __restrict__ ba,  const ushort* __restrict__ WT,
                     const float* __restrict__ c2,
                     float* __restrict__ pp, float* __restrict__ nn,
                     float* __restrict__ aa)     // each [2][N][R] partials
{
    __shared__ __align__(16) ushort lds[28672];    // 56 KB
    __shared__ float sPm[64], sNm[64];

    ushort* sX  = lds;             // phase1: [64][64]
    ushort* sW  = lds + 4096;      // phase1: [3][128][64]
    ushort* sH1 = lds;             // phase2: [64][128]
    ushort* sW2 = lds + 8192;      // phase2: [128][128]

    const ushort* W2pT = WT + 196608;
    const ushort* W2nT = WT + 212992;

    const int bid = blockIdx.x;
    const int n = bid >> 1, half = bid & 1;
    const int tid = threadIdx.x;
    const int w = tid >> 6, l = tid & 63, q = l >> 4, c = l & 15;

    const int c0 = C[2 * n], c1 = C[2 * n + 1];

    if (tid < 64) {
        int tg = half * 64 + tid;
        bool in = (tg >= c0) && (tg <= c1);
        sPm[tid] = in ? Pw[n * SEQ_ + tg] : 0.f;
        sNm[tid] = in ? 0.f : Nw[n * SEQ_ + tg];
    }

    // Tile activity (block-uniform). Tile mt covers global rows [lo, lo+15].
    bool needP[4], needN[4];
    bool anyP = false, anyN = false;
#pragma unroll
    for (int mt = 0; mt < 4; ++mt) {
        int lo = half * 64 + mt * 16, hi = lo + 15;
        needP[mt] = (hi >= c0) && (lo <= c1);          // overlaps region
        needN[mt] = !((lo >= c0) && (hi <= c1));       // not fully inside region
        anyP |= needP[mt]; anyN |= needN[mt];
    }

    f32x4 accP[4][2], accN[4][2], accA[4][2];
#pragma unroll
    for (int mt = 0; mt < 4; ++mt)
#pragma unroll
        for (int nt = 0; nt < 2; ++nt) { accP[mt][nt] = 0.f; accN[mt][nt] = 0.f; accA[mt][nt] = 0.f; }

    const float* Lbase = L + ((size_t)n * SEQ_ + half * 64) * E_;

    // Per-thread X staging geometry: thread handles rows xrow and xrow+32, k-seg xseg.
    const int xrow = tid >> 3, xseg = tid & 7;
    const int xst0 = xrow * 64 + (xseg ^ (xrow & 7)) * 8;   // (xrow+32)&7 == xrow&7
    const int xst1 = xst0 + 32 * 64;
    const float* gpA = Lbase + xrow * E_ + xseg * 8;

    // Prefetch X for chunk 0.
    float4 xv0, xv1, xv2, xv3;
    {
        const float* g0 = gpA;
        const float* g1 = gpA + 32 * E_;
        xv0 = *(const float4*)g0; xv1 = *(const float4*)(g0 + 4);
        xv2 = *(const float4*)g1; xv3 = *(const float4*)(g1 + 4);
    }

    for (int ch = 0; ch < 8; ++ch) {
        const int kb = ch * 64;
        // --- W DMA first (latency hides under X conversion) ---
#pragma unroll
        for (int j = 0; j < 12; ++j) {
            int gi = j * 4 + w;                // 0..47
            int s = gi >> 4, blk = gi & 15;
            if (s == 0 && !anyP) continue;
            if (s == 1 && !anyN) continue;
            int row = blk * 8 + (l >> 3);
            int kseg = (l & 7) ^ (row & 7);
            async16(&sW[(s * 128 + blk * 8) * 64], WT + s * 65536 + row * E_ + kb + kseg * 8);
        }
        // --- convert current X regs -> sX ---
        {
            union { short8 v; ushort u[8]; } t8;
            t8.u[0] = f2bf(xv0.x); t8.u[1] = f2bf(xv0.y); t8.u[2] = f2bf(xv0.z); t8.u[3] = f2bf(xv0.w);
            t8.u[4] = f2bf(xv1.x); t8.u[5] = f2bf(xv1.y); t8.u[6] = f2bf(xv1.z); t8.u[7] = f2bf(xv1.w);
            *(short8*)&sX[xst0] = t8.v;
            t8.u[0] = f2bf(xv2.x); t8.u[1] = f2bf(xv2.y); t8.u[2] = f2bf(xv2.z); t8.u[3] = f2bf(xv2.w);
            t8.u[4] = f2bf(xv3.x); t8.u[5] = f2bf(xv3.y); t8.u[6] = f2bf(xv3.z); t8.u[7] = f2bf(xv3.w);
            *(short8*)&sX[xst1] = t8.v;
        }
        // Pin issue order: all W DMA before the X prefetch (counted vmcnt depends on it).
        __builtin_amdgcn_sched_barrier(0);
        if (ch < 7) {
            const float* g0 = gpA + kb + 64;
            const float* g1 = g0 + 32 * E_;
            xv0 = *(const float4*)g0; xv1 = *(const float4*)(g0 + 4);
            xv2 = *(const float4*)g1; xv3 = *(const float4*)(g1 + 4);
            // Wait: W DMA + sX writes done; the 4 X prefetch loads stay in flight.
            asm volatile("s_waitcnt vmcnt(4) lgkmcnt(0)" ::: "memory");
        } else {
            asm volatile("s_waitcnt vmcnt(0) lgkmcnt(0)" ::: "memory");
        }
        __builtin_amdgcn_s_barrier();
        __builtin_amdgcn_sched_barrier(0);

#pragma unroll
        for (int k2 = 0; k2 < 2; ++k2) {
            short8 a[4];
#pragma unroll
            for (int mt = 0; mt < 4; ++mt) {
                int row = mt * 16 + c;
                a[mt] = *(const short8*)&sX[row * 64 + ((k2 * 4 + q) ^ (row & 7)) * 8];
            }
            const int r0 = w * 32 + c;
            const int r1 = r0 + 16;                     // (r1&7)==(r0&7)
            const int p0 = (k2 * 4 + q) ^ (r0 & 7);
            short8 bA0 = *(const short8*)&sW[(256 + r0) * 64 + p0 * 8];
            short8 bA1 = *(const short8*)&sW[(256 + r1) * 64 + p0 * 8];
#pragma unroll
            for (int mt = 0; mt < 4; ++mt) {
                accA[mt][0] = __builtin_amdgcn_mfma_f32_16x16x32_bf16(a[mt], bA0, accA[mt][0], 0, 0, 0);
                accA[mt][1] = __builtin_amdgcn_mfma_f32_16x16x32_bf16(a[mt], bA1, accA[mt][1], 0, 0, 0);
            }
            if (anyP) {
                short8 bP0 = *(const short8*)&sW[r0 * 64 + p0 * 8];
                short8 bP1 = *(const short8*)&sW[r1 * 64 + p0 * 8];
#pragma unroll
                for (int mt = 0; mt < 4; ++mt)
                    if (needP[mt]) {
                        accP[mt][0] = __builtin_amdgcn_mfma_f32_16x16x32_bf16(a[mt], bP0, accP[mt][0], 0, 0, 0);
                        accP[mt][1] = __builtin_amdgcn_mfma_f32_16x16x32_bf16(a[mt], bP1, accP[mt][1], 0, 0, 0);
                    }
            }
            if (anyN) {
                short8 bN0 = *(const short8*)&sW[(128 + r0) * 64 + p0 * 8];
                short8 bN1 = *(const short8*)&sW[(128 + r1) * 64 + p0 * 8];
#pragma unroll
                for (int mt = 0; mt < 4; ++mt)
                    if (needN[mt]) {
                        accN[mt][0] = __builtin_amdgcn_mfma_f32_16x16x32_bf16(a[mt], bN0, accN[mt][0], 0, 0, 0);
                        accN[mt][1] = __builtin_amdgcn_mfma_f32_16x16x32_bf16(a[mt], bN1, accN[mt][1], 0, 0, 0);
                    }
            }
        }
        if (ch < 7) asm volatile("s_waitcnt vmcnt(4) lgkmcnt(0)" ::: "memory");
        else        asm volatile("s_waitcnt vmcnt(0) lgkmcnt(0)" ::: "memory");
        __builtin_amdgcn_s_barrier();
        __builtin_amdgcn_sched_barrier(0);
    }

    // ---- A-set epilogue -> aa partial ----
#pragma unroll
    for (int nt = 0; nt < 2; ++nt) {
        int r = w * 32 + nt * 16 + c;
        float bar = ba[r];
        float s = 0.f;
#pragma unroll
        for (int mt = 0; mt < 4; ++mt)
#pragma unroll
            for (int i = 0; i < 4; ++i) {
                int t = mt * 16 + q * 4 + i;
                float m = sPm[t] + sNm[t];
                s += fast_tanhf(fmaf(m, accA[mt][nt][i], bar));
            }
        s += __shfl_xor(s, 16);
        s += __shfl_xor(s, 32);
        if (q == 0) aa[half * NR_ + n * R_ + r] = s * (1.f / SEQ_);
    }

    // ---- P then N ----
#pragma unroll
    for (int ps = 0; ps < 2; ++ps) {
        const f32x4 (*acc1)[2] = ps ? accN : accP;
        const float* sM  = ps ? sNm : sPm;
        const float* b1  = ps ? b1n : b1p;
        const float* b2  = ps ? b2n : b2p;
        const ushort* W2T = ps ? W2nT : W2pT;
        const float* c2x = c2 + ps * R_;
        float* outp = ps ? nn : pp;
        const bool any = ps ? anyN : anyP;
        const bool nd[4] = { ps ? needN[0] : needP[0], ps ? needN[1] : needP[1],
                             ps ? needN[2] : needP[2], ps ? needN[3] : needP[3] };

        f32x4 acc2[4][2];
#pragma unroll
        for (int mt = 0; mt < 4; ++mt)
#pragma unroll
            for (int nt = 0; nt < 2; ++nt) acc2[mt][nt] = 0.f;

        if (any) {
            __syncthreads();   // prior readers of lds done
#pragma unroll
            for (int nt = 0; nt < 2; ++nt) {
                int r = w * 32 + nt * 16 + c;
                float b1r = b1[r];
                int seg = r >> 3;
#pragma unroll
                for (int mt = 0; mt < 4; ++mt) {
                    if (!nd[mt]) continue;           // tile never read in phase-2 MFMA
#pragma unroll
                    for (int i = 0; i < 4; ++i) {
                        int t = mt * 16 + q * 4 + i;
                        float m = sM[t];
                        float h = (m == 0.f) ? 0.f : fast_tanhf(fmaf(m, acc1[mt][nt][i], b1r));
                        sH1[t * 128 + (seg ^ (t & 7)) * 8 + (r & 7)] = f2bf(h);
                    }
                }
            }
            // W2 (128x128) via DMA, 8 insts/wave
#pragma unroll
            for (int j = 0; j < 8; ++j) {
                int gi = j * 4 + w;                // 0..31
                int row = gi * 4 + (l >> 4);
                int kseg = (l & 15) ^ (row & 7);
                async16(&sW2[gi * 512], W2T + row * 128 + kseg * 8);
            }
            __syncthreads();

#pragma unroll
            for (int k2 = 0; k2 < 4; ++k2) {
                const int r0 = w * 32 + c;
                const int r1 = r0 + 16;
                const int p0 = (k2 * 4 + q) ^ (r0 & 7);
                short8 bf0 = *(const short8*)&sW2[r0 * 128 + p0 * 8];
                short8 bf1 = *(const short8*)&sW2[r1 * 128 + p0 * 8];
#pragma unroll
                for (int mt = 0; mt < 4; ++mt) {
                    if (!nd[mt]) continue;
                    int row = mt * 16 + c;
                    short8 af = *(const short8*)&sH1[row * 128 + ((k2 * 4 + q) ^ (row & 7)) * 8];
                    acc2[mt][0] = __builtin_amdgcn_mfma_f32_16x16x32_bf16(af, bf0, acc2[mt][0], 0, 0, 0);
                    acc2[mt][1] = __builtin_amdgcn_mfma_f32_16x16x32_bf16(af, bf1, acc2[mt][1], 0, 0, 0);
                }
            }
        }

#pragma unroll
        for (int nt = 0; nt < 2; ++nt) {
            int r = w * 32 + nt * 16 + c;
            float b2r = b2[r];
            float tc = fast_tanhf(c2x[r] + b2r);     // constant row for masked t
            float s = 0.f;
#pragma unroll
            for (int mt = 0; mt < 4; ++mt)
#pragma unroll
                for (int i = 0; i < 4; ++i) {
                    int t = mt * 16 + q * 4 + i;
                    float m = sM[t];
                    s += (m == 0.f) ? tc : fast_tanhf(acc2[mt][nt][i] + b2r);
                }
            s += __shfl_xor(s, 16);
            s += __shfl_xor(s, 32);
            if (q == 0) outp[half * NR_ + n * R_ + r] = s * (1.f / SEQ_);
        }
    }
}

// ---- combine ff halves -> d_out ----
__global__ __launch_bounds__(256)
void ffcomb_kernel(const float* __restrict__ aa, float* __restrict__ out)
{
    int i = (blockIdx.x * 256 + threadIdx.x) * 4;
    float4 a0 = *(const float4*)(aa + i);
    float4 a1 = *(const float4*)(aa + NR_ + i);
    float4 o; o.x = a0.x + a1.x; o.y = a0.y + a1.y; o.z = a0.z + a1.z; o.w = a0.w + a1.w;
    *(float4*)(out + i) = o;
}

// ---- pairwise exp(-dist): 64i x 32j tile per block, per-block partials (no atomics) ----
__global__ __launch_bounds__(256, 2)
void sim_kernel(const float* __restrict__ pp, const float* __restrict__ nn,
                float* __restrict__ simP, float* __restrict__ simN)
{
    __shared__ __align__(16) float sPi[64][133];
    __shared__ __align__(16) float sPj[32][133];
    __shared__ __align__(16) float sNj[32][133];

    const int jb = blockIdx.x;   // 0..63
    const int ib = blockIdx.y;   // 0..31
    const int tid = threadIdx.x;

#pragma unroll
    for (int it = 0; it < 8; ++it) {
        int idx = it * 256 + tid;
        int row = idx >> 5, seg = idx & 31;
        int g = (ib * 64 + row) * R_ + seg * 4;
        float4 a = *(const float4*)(pp + g);
        float4 b = *(const float4*)(pp + NR_ + g);
        a.x += b.x; a.y += b.y; a.z += b.z; a.w += b.w;
        *(float4*)&sPi[row][seg * 4] = a;
    }
#pragma unroll
    for (int it = 0; it < 4; ++it) {
        int idx = it * 256 + tid;
        int row = idx >> 5, seg = idx & 31;
        int g = (jb * 32 + row) * R_ + seg * 4;
        float4 a = *(const float4*)(pp + g);
        float4 b = *(const float4*)(pp + NR_ + g);
        a.x += b.x; a.y += b.y; a.z += b.z; a.w += b.w;
        *(float4*)&sPj[row][seg * 4] = a;
        float4 u = *(const float4*)(nn + g);
        float4 v = *(const float4*)(nn + NR_ + g);
        u.x += v.x; u.y += v.y; u.z += v.z; u.w += v.w;
        *(float4*)&sNj[row][seg * 4] = u;
    }
    __syncthreads();

    const int ty = tid >> 4, tx = tid & 15;
    float d2p[4][2] = {}, d2n[4][2] = {};

    for (int rr = 0; rr < R_; rr += 4) {
        float4 xi[4], pj[2], nj[2];
#pragma unroll
        for (int a = 0; a < 4; ++a) xi[a] = *(const float4*)&sPi[ty * 4 + a][rr];
#pragma unroll
        for (int b = 0; b < 2; ++b) {
            pj[b] = *(const float4*)&sPj[tx * 2 + b][rr];
            nj[b] = *(const float4*)&sNj[tx * 2 + b][rr];
        }
#pragma unroll
        for (int a = 0; a < 4; ++a)
#pragma unroll
            for (int b = 0; b < 2; ++b) {
                float dx;
                dx = xi[a].x - pj[b].x; d2p[a][b] = fmaf(dx, dx, d2p[a][b]);
                dx = xi[a].y - pj[b].y; d2p[a][b] = fmaf(dx, dx, d2p[a][b]);
                dx = xi[a].z - pj[b].z; d2p[a][b] = fmaf(dx, dx, d2p[a][b]);
                dx = xi[a].w - pj[b].w; d2p[a][b] = fmaf(dx, dx, d2p[a][b]);
                dx = xi[a].x - nj[b].x; d2n[a][b] = fmaf(dx, dx, d2n[a][b]);
                dx = xi[a].y - nj[b].y; d2n[a][b] = fmaf(dx, dx, d2n[a][b]);
                dx = xi[a].z - nj[b].z; d2n[a][b] = fmaf(dx, dx, d2n[a][b]);
                dx = xi[a].w - nj[b].w; d2n[a][b] = fmaf(dx, dx, d2n[a][b]);
            }
    }

    float sp = 0.f, sn = 0.f;
#pragma unroll
    for (int a = 0; a < 4; ++a)
#pragma unroll
        for (int b = 0; b < 2; ++b) {
            sp += __expf(-sqrtf(d2p[a][b]));
            sn += __expf(-sqrtf(d2n[a][b]));
        }

#pragma unroll
    for (int off = 32; off; off >>= 1) {
        sp += __shfl_down(sp, off);
        sn += __shfl_down(sn, off);
    }
    __shared__ float redP[4], redN[4];
    const int wave = tid >> 6, lane = tid & 63;
    if (lane == 0) { redP[wave] = sp; redN[wave] = sn; }
    __syncthreads();
    if (tid == 0) {
        int bidl = ib * 64 + jb;
        simP[bidl] = redP[0] + redP[1] + redP[2] + redP[3];
        simN[bidl] = redN[0] + redN[1] + redN[2] + redN[3];
    }
}

__global__ __launch_bounds__(256)
void finalize_kernel(const float* __restrict__ simP, const float* __restrict__ simN,
                     float* __restrict__ out)
{
    const int tid = threadIdx.x;
    double sp = 0.0, sn = 0.0;
    for (int i = tid; i < 2048; i += 256) { sp += (double)simP[i]; sn += (double)simN[i]; }
    __shared__ double rp[256], rn[256];
    rp[tid] = sp; rn[tid] = sn;
    __syncthreads();
    for (int s = 128; s; s >>= 1) {
        if (tid < s) { rp[tid] += rp[tid + s]; rn[tid] += rn[tid + s]; }
        __syncthreads();
    }
    if (tid == 0) out[NR_] = (float)(-log(rp[0] / rn[0]));
}

extern "C" void kernel_launch(void* const* d_in, const int* in_sizes, int n_in,
                              void* d_out, int out_size, void* d_ws, size_t ws_size,
                              hipStream_t stream)
{
    const int*   C   = (const int*)  d_in[0];
    const float* L   = (const float*)d_in[1];
    const float* Pw  = (const float*)d_in[2];
    const float* Nw  = (const float*)d_in[3];
    const float* W1p = (const float*)d_in[4];
    const float* b1p = (const float*)d_in[5];
    const float* W2p = (const float*)d_in[6];
    const float* b2p = (const float*)d_in[7];
    const float* W1n = (const float*)d_in[8];
    const float* b1n = (const float*)d_in[9];
    const float* W2n = (const float*)d_in[10];
    const float* b2n = (const float*)d_in[11];
    const float* Wa  = (const float*)d_in[12];
    const float* ba  = (const float*)d_in[13];

    float* out = (float*)d_out;
    float* pp  = (float*)d_ws;            // [2][N][R]
    float* nn  = pp + 2 * NR_;            // [2][N][R]
    float* aa  = nn + 2 * NR_;            // [2][N][R]
    float* simP = aa + 2 * NR_;           // [2048]
    float* simN = simP + 2048;            // [2048]
    ushort* WT = (ushort*)((char*)d_ws + 6 * (size_t)NR_ * 4 + 65536);   // 448 KB
    float* c2  = (float*)(WT + 229376);   // [2][128]

    hipLaunchKernelGGL(prep_kernel, dim3(897), dim3(256), 0, stream,
                       W1p, W1n, Wa, W2p, W2n, b1p, b1n, WT, c2);
    hipLaunchKernelGGL(mlp_mfma_kernel, dim3(2 * N_), dim3(256), 0, stream,
                       C, L, Pw, Nw, b1p, b2p, b1n, b2n, ba, WT, c2, pp, nn, aa);
    hipLaunchKernelGGL(ffcomb_kernel, dim3(NR_ / 1024), dim3(256), 0, stream, aa, out);
    hipLaunchKernelGGL(sim_kernel, dim3(64, 32), dim3(256), 0, stream,
                       pp, nn, simP, simN);
    hipLaunchKernelGGL(finalize_kernel, dim3(1), dim3(256), 0, stream, simP, simN, out);
}

// Round 2
// 920.665 us; speedup vs baseline: 1.0104x; 1.0104x over previous
//
#include <hip/hip_runtime.h>
#include <math.h>

#define N_   2048
#define SEQ_ 128
#define E_   512
#define R_   128
#define NR_  (N_ * R_)

typedef __attribute__((ext_vector_type(8))) short short8;
typedef __attribute__((ext_vector_type(4))) float f32x4;

typedef __attribute__((address_space(3))) void lds_t;
typedef __attribute__((address_space(1))) const void glb_t;

__device__ __forceinline__ void async16(void* l, const void* g) {
    // 16B per lane: LDS dest = uniform base + lane*16; global src per-lane.
    __builtin_amdgcn_global_load_lds((glb_t*)g, (lds_t*)l, 16, 0, 0);
}

__device__ __forceinline__ ushort f2bf(float f) {
    union { float f; uint u; } v; v.f = f;
    uint r = v.u + 0x7FFFu + ((v.u >> 16) & 1u);   // RNE
    return (ushort)(r >> 16);
}
__device__ __forceinline__ float fast_tanhf(float x) {
    float ax = fabsf(x);
    float t = __expf(-2.f * ax);
    float r = (1.f - t) / (1.f + t);
    return copysignf(r, x);
}

// ---- prep: W^T bf16: three ExR -> [128][512]; two RxR -> [128][128] ----
__global__ void prep_kernel(const float* __restrict__ W1p, const float* __restrict__ W1n,
                            const float* __restrict__ Wa,  const float* __restrict__ W2p,
                            const float* __restrict__ W2n, ushort* __restrict__ WT)
{
    int idx = blockIdx.x * 256 + threadIdx.x;      // 0..229375
    if (idx < 196608) {
        int m = idx >> 16;
        int o = idx & 65535;
        int r = o >> 9, e = o & 511;
        const float* src = (m == 0) ? W1p : (m == 1) ? W1n : Wa;
        WT[idx] = f2bf(src[e * R_ + r]);
    } else if (idx < 229376) {
        int o = idx - 196608;
        int m = o >> 14;
        int p = o & 16383;
        int r = p >> 7, e = p & 127;
        const float* src = (m == 0) ? W2p : W2n;
        WT[idx] = f2bf(src[e * R_ + r]);
    }
}

// One block per (n, half). Wave w owns t-rows [w*16, w*16+16), ALL 128 r.
// X goes global -> registers -> MFMA A-frag directly (no LDS staging).
// W staged in 48KB LDS via global_load_lds; XOR-swizzled rows (proven pattern).
// 3 blocks/CU (48.5KB LDS, VGPR-capped via launch_bounds).
__global__ __launch_bounds__(256, 3)
void mlp_mfma_kernel(const int* __restrict__ C, const float* __restrict__ L,
                     const float* __restrict__ Pw, const float* __restrict__ Nw,
                     const float* __restrict__ b1p, const float* __restrict__ b2p,
                     const float* __restrict__ b1n, const float* __restrict__ b2n,
                     const float* __restrict__ ba,  const ushort* __restrict__ WT,
                     float* __restrict__ pp, float* __restrict__ nn,
                     float* __restrict__ aa)     // each [2][N][R] partials
{
    // phase1: sW [3][128][64] bf16 = 48KB at lds[0..24576)
    // phase2: sW2 [128][128] = 32KB at lds[0..16384); sH1 4 waves x [16][128] = 16KB at lds[16384..24576)
    __shared__ __align__(16) ushort lds[24576];
    __shared__ float sRed[4][128];
    __shared__ float sPm[64], sNm[64];

    const ushort* W2pT = WT + 196608;
    const ushort* W2nT = WT + 212992;

    const int bid = blockIdx.x;
    const int n = bid >> 1, half = bid & 1;
    const int tid = threadIdx.x;
    const int w = tid >> 6, l = tid & 63, q = l >> 4, c = l & 15;

    if (tid < 64) {
        int tg = half * 64 + tid;
        int c0 = C[2 * n], c1 = C[2 * n + 1];
        bool in = (tg >= c0) && (tg <= c1);
        sPm[tid] = in ? Pw[n * SEQ_ + tg] : 0.f;
        sNm[tid] = in ? 0.f : Nw[n * SEQ_ + tg];
    }

    f32x4 accP[8], accN[8], accA[8];
#pragma unroll
    for (int nt = 0; nt < 8; ++nt) { accP[nt] = 0.f; accN[nt] = 0.f; accA[nt] = 0.f; }

    // This thread's A-row of L: row = n*128 + half*64 + w*16 + c, k-offset q*8.
    const float* Lrow = L + ((size_t)(n * SEQ_ + half * 64 + w * 16 + c)) * E_ + q * 8;

    for (int ch = 0; ch < 8; ++ch) {
        const int kb = ch * 64;
        // --- W DMA: 3 sets x 128 rows x 64 k, 12 insts/wave (proven round-0 code) ---
#pragma unroll
        for (int j = 0; j < 12; ++j) {
            int gi = j * 4 + w;                // 0..47
            int s = gi >> 4, blk = gi & 15;
            int row = blk * 8 + (l >> 3);
            int kseg = (l & 7) ^ (row & 7);
            async16(&lds[(s * 128 + blk * 8) * 64], WT + s * 65536 + row * E_ + kb + kseg * 8);
        }
        // --- X: global -> regs -> bf16 A-frags (lane c = A-row, q = k-chunk) ---
        const float* p0 = Lrow + kb;
        float4 xa = *(const float4*)p0;
        float4 xb = *(const float4*)(p0 + 4);
        float4 xc = *(const float4*)(p0 + 32);
        float4 xd = *(const float4*)(p0 + 36);
        short8 af0, af1;
        {
            union { short8 v; ushort u[8]; } t8;
            t8.u[0] = f2bf(xa.x); t8.u[1] = f2bf(xa.y); t8.u[2] = f2bf(xa.z); t8.u[3] = f2bf(xa.w);
            t8.u[4] = f2bf(xb.x); t8.u[5] = f2bf(xb.y); t8.u[6] = f2bf(xb.z); t8.u[7] = f2bf(xb.w);
            af0 = t8.v;
            t8.u[0] = f2bf(xc.x); t8.u[1] = f2bf(xc.y); t8.u[2] = f2bf(xc.z); t8.u[3] = f2bf(xc.w);
            t8.u[4] = f2bf(xd.x); t8.u[5] = f2bf(xd.y); t8.u[6] = f2bf(xd.z); t8.u[7] = f2bf(xd.w);
            af1 = t8.v;
        }
        __syncthreads();

#pragma unroll
        for (int k2 = 0; k2 < 2; ++k2) {
            short8 a = k2 ? af1 : af0;
            const int p = ((k2 * 4 + q) ^ (c & 7)) * 8;
#pragma unroll
            for (int nt = 0; nt < 8; ++nt) {
                int ro = (nt * 16 + c) * 64 + p;
                short8 bP = *(const short8*)&lds[ro];
                short8 bN = *(const short8*)&lds[8192 + ro];
                short8 bA = *(const short8*)&lds[16384 + ro];
                accP[nt] = __builtin_amdgcn_mfma_f32_16x16x32_bf16(a, bP, accP[nt], 0, 0, 0);
                accN[nt] = __builtin_amdgcn_mfma_f32_16x16x32_bf16(a, bN, accN[nt], 0, 0, 0);
                accA[nt] = __builtin_amdgcn_mfma_f32_16x16x32_bf16(a, bA, accA[nt], 0, 0, 0);
            }
        }
        __syncthreads();
    }

    // ---- A-set epilogue: per-wave partial over its 16 t-rows -> sRed -> aa ----
#pragma unroll
    for (int nt = 0; nt < 8; ++nt) {
        int r = nt * 16 + c;
        float bar = ba[r];
        float s = 0.f;
#pragma unroll
        for (int i = 0; i < 4; ++i) {
            int t = w * 16 + q * 4 + i;
            float m = sPm[t] + sNm[t];
            s += fast_tanhf(fmaf(m, accA[nt][i], bar));
        }
        s += __shfl_xor(s, 16);
        s += __shfl_xor(s, 32);
        if (q == 0) sRed[w][r] = s;
    }
    __syncthreads();
    if (tid < 128) {
        float v = sRed[0][tid] + sRed[1][tid] + sRed[2][tid] + sRed[3][tid];
        aa[half * NR_ + n * R_ + tid] = v * (1.f / SEQ_);
    }

    // ---- P then N (statically instantiated to keep acc arrays in registers) ----
    {
        ushort* sH1w = &lds[16384 + w * 2048];

#pragma unroll
        for (int ps = 0; ps < 2; ++ps) {
            const float* sM  = ps ? sNm : sPm;
            const float* b1  = ps ? b1n : b1p;
            const float* b2  = ps ? b2n : b2p;
            const ushort* W2T = ps ? W2nT : W2pT;
            float* outp = ps ? nn : pp;

            __syncthreads();   // sRed readers + prior LDS readers done

            // h1 -> wave-private sH1 [16][128], XOR-swizzled 16B segs
#pragma unroll
            for (int nt = 0; nt < 8; ++nt) {
                int r = nt * 16 + c;
                float b1r = b1[r];
                int rseg = r >> 3;
#pragma unroll
                for (int i = 0; i < 4; ++i) {
                    int t = q * 4 + i;   // local t-row 0..15
                    float m = sM[w * 16 + t];
                    float acc = ps ? accN[nt][i] : accP[nt][i];
                    float h = fast_tanhf(fmaf(m, acc, b1r));
                    int seg = rseg ^ (t & 7);
                    sH1w[t * 128 + seg * 8 + (c & 7)] = f2bf(h);
                }
            }
            // W2 (128x128) DMA, 8 insts/wave (proven round-0 code)
#pragma unroll
            for (int j = 0; j < 8; ++j) {
                int gi = j * 4 + w;                // 0..31
                int row = gi * 4 + (l >> 4);
                int kseg = (l & 15) ^ (row & 7);
                async16(&lds[gi * 512], W2T + row * 128 + kseg * 8);
            }
            __syncthreads();

            f32x4 acc2[8];
#pragma unroll
            for (int nt = 0; nt < 8; ++nt) acc2[nt] = 0.f;

#pragma unroll
            for (int k2 = 0; k2 < 4; ++k2) {
                const int p = ((k2 * 4 + q) ^ (c & 7)) * 8;
                short8 a = *(const short8*)&sH1w[c * 128 + p];
#pragma unroll
                for (int nt = 0; nt < 8; ++nt) {
                    short8 b = *(const short8*)&lds[(nt * 16 + c) * 128 + p];
                    acc2[nt] = __builtin_amdgcn_mfma_f32_16x16x32_bf16(a, b, acc2[nt], 0, 0, 0);
                }
            }

#pragma unroll
            for (int nt = 0; nt < 8; ++nt) {
                int r = nt * 16 + c;
                float b2r = b2[r];
                float s = 0.f;
#pragma unroll
                for (int i = 0; i < 4; ++i)
                    s += fast_tanhf(acc2[nt][i] + b2r);
                s += __shfl_xor(s, 16);
                s += __shfl_xor(s, 32);
                if (q == 0) sRed[w][r] = s;
            }
            __syncthreads();
            if (tid < 128) {
                float v = sRed[0][tid] + sRed[1][tid] + sRed[2][tid] + sRed[3][tid];
                outp[half * NR_ + n * R_ + tid] = v * (1.f / SEQ_);
            }
        }
    }
}

// ---- combine ff halves -> d_out ----
__global__ __launch_bounds__(256)
void ffcomb_kernel(const float* __restrict__ aa, float* __restrict__ out)
{
    int i = (blockIdx.x * 256 + threadIdx.x) * 4;
    float4 a0 = *(const float4*)(aa + i);
    float4 a1 = *(const float4*)(aa + NR_ + i);
    float4 o; o.x = a0.x + a1.x; o.y = a0.y + a1.y; o.z = a0.z + a1.z; o.w = a0.w + a1.w;
    *(float4*)(out + i) = o;
}

// ---- pairwise exp(-dist): 64i x 32j tile per block, per-block partials (no atomics) ----
__global__ __launch_bounds__(256, 2)
void sim_kernel(const float* __restrict__ pp, const float* __restrict__ nn,
                float* __restrict__ simP, float* __restrict__ simN)
{
    __shared__ __align__(16) float sPi[64][133];
    __shared__ __align__(16) float sPj[32][133];
    __shared__ __align__(16) float sNj[32][133];

    const int jb = blockIdx.x;   // 0..63
    const int ib = blockIdx.y;   // 0..31
    const int tid = threadIdx.x;

#pragma unroll
    for (int it = 0; it < 8; ++it) {
        int idx = it * 256 + tid;
        int row = idx >> 5, seg = idx & 31;
        int g = (ib * 64 + row) * R_ + seg * 4;
        float4 a = *(const float4*)(pp + g);
        float4 b = *(const float4*)(pp + NR_ + g);
        a.x += b.x; a.y += b.y; a.z += b.z; a.w += b.w;
        *(float4*)&sPi[row][seg * 4] = a;
    }
#pragma unroll
    for (int it = 0; it < 4; ++it) {
        int idx = it * 256 + tid;
        int row = idx >> 5, seg = idx & 31;
        int g = (jb * 32 + row) * R_ + seg * 4;
        float4 a = *(const float4*)(pp + g);
        float4 b = *(const float4*)(pp + NR_ + g);
        a.x += b.x; a.y += b.y; a.z += b.z; a.w += b.w;
        *(float4*)&sPj[row][seg * 4] = a;
        float4 u = *(const float4*)(nn + g);
        float4 v = *(const float4*)(nn + NR_ + g);
        u.x += v.x; u.y += v.y; u.z += v.z; u.w += v.w;
        *(float4*)&sNj[row][seg * 4] = u;
    }
    __syncthreads();

    const int ty = tid >> 4, tx = tid & 15;
    float d2p[4][2] = {}, d2n[4][2] = {};

    for (int rr = 0; rr < R_; rr += 4) {
        float4 xi[4], pj[2], nj[2];
#pragma unroll
        for (int a = 0; a < 4; ++a) xi[a] = *(const float4*)&sPi[ty * 4 + a][rr];
#pragma unroll
        for (int b = 0; b < 2; ++b) {
            pj[b] = *(const float4*)&sPj[tx * 2 + b][rr];
            nj[b] = *(const float4*)&sNj[tx * 2 + b][rr];
        }
#pragma unroll
        for (int a = 0; a < 4; ++a)
#pragma unroll
            for (int b = 0; b < 2; ++b) {
                float dx;
                dx = xi[a].x - pj[b].x; d2p[a][b] = fmaf(dx, dx, d2p[a][b]);
                dx = xi[a].y - pj[b].y; d2p[a][b] = fmaf(dx, dx, d2p[a][b]);
                dx = xi[a].z - pj[b].z; d2p[a][b] = fmaf(dx, dx, d2p[a][b]);
                dx = xi[a].w - pj[b].w; d2p[a][b] = fmaf(dx, dx, d2p[a][b]);
                dx = xi[a].x - nj[b].x; d2n[a][b] = fmaf(dx, dx, d2n[a][b]);
                dx = xi[a].y - nj[b].y; d2n[a][b] = fmaf(dx, dx, d2n[a][b]);
                dx = xi[a].z - nj[b].z; d2n[a][b] = fmaf(dx, dx, d2n[a][b]);
                dx = xi[a].w - nj[b].w; d2n[a][b] = fmaf(dx, dx, d2n[a][b]);
            }
    }

    float sp = 0.f, sn = 0.f;
#pragma unroll
    for (int a = 0; a < 4; ++a)
#pragma unroll
        for (int b = 0; b < 2; ++b) {
            sp += __expf(-sqrtf(d2p[a][b]));
            sn += __expf(-sqrtf(d2n[a][b]));
        }

#pragma unroll
    for (int off = 32; off; off >>= 1) {
        sp += __shfl_down(sp, off);
        sn += __shfl_down(sn, off);
    }
    __shared__ float redP[4], redN[4];
    const int wave = tid >> 6, lane = tid & 63;
    if (lane == 0) { redP[wave] = sp; redN[wave] = sn; }
    __syncthreads();
    if (tid == 0) {
        int bidl = ib * 64 + jb;
        simP[bidl] = redP[0] + redP[1] + redP[2] + redP[3];
        simN[bidl] = redN[0] + redN[1] + redN[2] + redN[3];
    }
}

__global__ __launch_bounds__(256)
void finalize_kernel(const float* __restrict__ simP, const float* __restrict__ simN,
                     float* __restrict__ out)
{
    const int tid = threadIdx.x;
    double sp = 0.0, sn = 0.0;
    for (int i = tid; i < 2048; i += 256) { sp += (double)simP[i]; sn += (double)simN[i]; }
    __shared__ double rp[256], rn[256];
    rp[tid] = sp; rn[tid] = sn;
    __syncthreads();
    for (int s = 128; s; s >>= 1) {
        if (tid < s) { rp[tid] += rp[tid + s]; rn[tid] += rn[tid + s]; }
        __syncthreads();
    }
    if (tid == 0) out[NR_] = (float)(-log(rp[0] / rn[0]));
}

extern "C" void kernel_launch(void* const* d_in, const int* in_sizes, int n_in,
                              void* d_out, int out_size, void* d_ws, size_t ws_size,
                              hipStream_t stream)
{
    const int*   C   = (const int*)  d_in[0];
    const float* L   = (const float*)d_in[1];
    const float* Pw  = (const float*)d_in[2];
    const float* Nw  = (const float*)d_in[3];
    const float* W1p = (const float*)d_in[4];
    const float* b1p = (const float*)d_in[5];
    const float* W2p = (const float*)d_in[6];
    const float* b2p = (const float*)d_in[7];
    const float* W1n = (const float*)d_in[8];
    const float* b1n = (const float*)d_in[9];
    const float* W2n = (const float*)d_in[10];
    const float* b2n = (const float*)d_in[11];
    const float* Wa  = (const float*)d_in[12];
    const float* ba  = (const float*)d_in[13];

    float* out = (float*)d_out;
    float* pp  = (float*)d_ws;            // [2][N][R]
    float* nn  = pp + 2 * NR_;            // [2][N][R]
    float* aa  = nn + 2 * NR_;            // [2][N][R]
    float* simP = aa + 2 * NR_;           // [2048]
    float* simN = simP + 2048;            // [2048]
    ushort* WT = (ushort*)((char*)d_ws + 6 * (size_t)NR_ * 4 + 65536);   // 448 KB

    hipLaunchKernelGGL(prep_kernel, dim3(896), dim3(256), 0, stream,
                       W1p, W1n, Wa, W2p, W2n, WT);
    hipLaunchKernelGGL(mlp_mfma_kernel, dim3(2 * N_), dim3(256), 0, stream,
                       C, L, Pw, Nw, b1p, b2p, b1n, b2n, ba, WT, pp, nn, aa);
    hipLaunchKernelGGL(ffcomb_kernel, dim3(NR_ / 1024), dim3(256), 0, stream, aa, out);
    hipLaunchKernelGGL(sim_kernel, dim3(64, 32), dim3(256), 0, stream,
                       pp, nn, simP, simN);
    hipLaunchKernelGGL(finalize_kernel, dim3(1), dim3(256), 0, stream, simP, simN, out);
}